// Round 12
// baseline (562.755 us; speedup 1.0000x reference)
//
#include <hip/hip_runtime.h>
#include <stdint.h>

#define SEQ 8192
#define CS 64                       // chunk length == block row tile
#define NCH 128                     // chunks per sequence
#define NBLK 4096                   // 32 batches * 128 chunks

typedef float f32x4 __attribute__((ext_vector_type(4)));
typedef short short8 __attribute__((ext_vector_type(8)));
typedef unsigned short u16;
typedef u16 ushort8 __attribute__((ext_vector_type(8)));
typedef u16 ushort4v __attribute__((ext_vector_type(4)));

__device__ __forceinline__ u16 f2bf(float f) {
  uint32_t u = __float_as_uint(f);
  u += 0x7fffu + ((u >> 16) & 1u);   // round-to-nearest-even
  return (u16)(u >> 16);
}

// ---------- emb f32 -> bf16 table (one-time) ----------
__global__ void embq_kernel(const float* __restrict__ emb, u16* __restrict__ embq) {
  int i = (blockIdx.x * 256 + threadIdx.x) * 4;   // 8,192,000 elements exactly
  float4 v = *(const float4*)(emb + i);
  ushort4v p;
  p[0] = f2bf(v.x); p[1] = f2bf(v.y); p[2] = f2bf(v.z); p[3] = f2bf(v.w);
  *(ushort4v*)(embq + i) = p;
}

// ---------- weight preprocess: f32 [l][k][d] -> bf16 swizzled 8KB tiles ----------
// WtS: 64 tiles of 8192 BYTES, tile index (mat*4 + dh)*4 + kt, in-tile [64 dloc][64 kl],
// byte = (dloc*128 + kl*2) ^ ((dloc&7)<<4).  mat: 0=Wz l0,1=Wz l1,2=Wh l0,3=Wh l1
__global__ void wt_kernel(const float* __restrict__ Wz, const float* __restrict__ Wh,
                          u16* __restrict__ WtS) {
  int idx = blockIdx.x * 256 + threadIdx.x;   // 4*65536
  int d = idx & 255;
  int k = (idx >> 8) & 255;
  int m = idx >> 16;
  const float* src = (m < 2 ? Wz : Wh) + (size_t)(m & 1) * 65536;
  float v = src[k * 256 + d];
  int dh = d >> 6, dloc = d & 63, kt = k >> 6, kl = k & 63;
  size_t tile = ((size_t)(m * 4 + dh) * 4 + kt) * 8192;   // BYTES
  size_t byte = (size_t)((dloc * 128 + kl * 2) ^ ((dloc & 7) << 4));
  *(u16*)((char*)WtS + tile + byte) = f2bf(v);
}

// ---- barrier-free MFMA core: A from LDS, B fragments direct from global (L2-hot) ----
// wave (wr,wc): rows [wr*32, wr*32+32), d in [wc*64, wc*64+64) -> B dh-tile = wc.
__device__ __forceinline__ void gemm_core_g(int lsel, const char* WtSb,
    const u16* As, int wr, int wc, int l15, int lg,
    f32x4 (&accz)[2][4], f32x4 (&acch)[2][4])
{
  const int xm = (l15 & 7) << 4;
  const char* basez = WtSb + (size_t)((lsel * 4 + wc) * 4) * 8192;
  const char* baseh = WtSb + (size_t)(((2 + lsel) * 4 + wc) * 4) * 8192;
  for (int kt = 0; kt < 4; kt++) {
    #pragma unroll
    for (int ks = 0; ks < 2; ks++) {
      short8 fa[2];
      #pragma unroll
      for (int mi = 0; mi < 2; mi++)
        fa[mi] = *(const short8*)((const char*)As + kt * 8192 +
                   (((wr * 32 + mi * 16 + l15) * 128 + ks * 64 + lg * 16) ^ xm));
      #pragma unroll
      for (int ni = 0; ni < 4; ni++) {
        const int off = (((ni * 16 + l15) * 128 + ks * 64 + lg * 16) ^ xm);
        short8 fbz = *(const short8*)(basez + kt * 8192 + off);
        short8 fbh = *(const short8*)(baseh + kt * 8192 + off);
        #pragma unroll
        for (int mi = 0; mi < 2; mi++) {
          accz[mi][ni] = __builtin_amdgcn_mfma_f32_16x16x32_bf16(fa[mi], fbz, accz[mi][ni], 0, 0, 0);
          acch[mi][ni] = __builtin_amdgcn_mfma_f32_16x16x32_bf16(fa[mi], fbh, acch[mi][ni], 0, 0, 0);
        }
      }
    }
  }
}

// SegT addressing (overlays As): seg row 2048B, XOR-swizzled by seg to spread banks
__device__ __forceinline__ float2* seg_ptr(char* segt, int s, int d) {
  return (float2*)(segt + s * 2048 + ((d * 8) ^ (s << 4)));
}

// ---------- unified GEMM kernel ----------
// Block: 512 threads (8 waves: wr=w>>2 rows, wc=w&3 cols), 64 rows x 256 d, K=256.
// PHASE 0: gemm0 -> chunk-local (A,B) totals -> Ap0/Bs0.
// PHASE 1: gemm0 recompute (a,b in regs) + carry -> rebuild h1 in LDS -> gemm1 -> Ap1/Bs1.
template<int PHASE>
__global__ __launch_bounds__(512, 4)
void gru_kernel(const int* __restrict__ x, const u16* __restrict__ embq,
                const u16* __restrict__ WtS,
                const float* __restrict__ bz0, const float* __restrict__ bh0,
                const float* __restrict__ bz1, const float* __restrict__ bh1,
                const float* __restrict__ carry,
                float* __restrict__ Ap, float* __restrict__ Bs)
{
  __shared__ __align__(16) u16 As[16384];    // 32KB: 4 kt-subtiles [64t][64k] swz; SegT overlay

  const int tid = threadIdx.x;
  const int lane = tid & 63;
  const int w = tid >> 6;
  const int wr = w >> 2, wc = w & 3;         // 2 row-groups x 4 col-groups
  const int l15 = lane & 15, lg = lane >> 4;
  const int cb = blockIdx.x;
  const int b = cb >> 7, c = cb & (NCH - 1);
  const char* WtSb = (const char*)WtS;
  char* segt = (char*)As;

  // ---- A gather: 64 rows x 256 k; thread = (row sm=tid>>3, 32-k chunk kq=tid&7) ----
  {
    const int sm = tid >> 3, kq = tid & 7;
    const int tok = x[b * SEQ + c * CS + sm];
    const u16* src = embq + (size_t)tok * 256 + kq * 32;
    char* sub = (char*)As + (kq >> 1) * 8192;
    const int kb = (kq & 1) * 64;
    const int swz = (sm & 7) << 4;
    #pragma unroll
    for (int j = 0; j < 4; j++) {
      ushort8 p = *(const ushort8*)(src + j * 8);
      *(ushort8*)(sub + ((sm * 128 + kb + j * 16) ^ swz)) = p;
    }
  }

  f32x4 accz[2][4], acch[2][4];
  #pragma unroll
  for (int i = 0; i < 2; i++)
    #pragma unroll
    for (int j = 0; j < 4; j++) {
      f32x4 zz = {0.f, 0.f, 0.f, 0.f};
      accz[i][j] = zz; acch[i][j] = zz;
    }

  __syncthreads();                           // As ready
  gemm_core_g(0, WtSb, As, wr, wc, l15, lg, accz, acch);
  __syncthreads();                           // all MFMA done; As free for SegT

  // ---- layer-0 gates -> SegT (PHASE1 keeps a,b in regs) ----
  #pragma unroll
  for (int ni = 0; ni < 4; ni++) {
    const int d = wc * 64 + ni * 16 + l15;
    const float bzv = bz0[d];
    const float bhv = bh0[d];
    #pragma unroll
    for (int mi = 0; mi < 2; mi++) {
      float A = 1.f, B = 0.f;
      #pragma unroll
      for (int r = 0; r < 4; r++) {
        float zl = accz[mi][ni][r] + bzv;
        float zg = 1.f / (1.f + __expf(-zl));
        float ht = acch[mi][ni][r] + bhv;
        float a = 1.f - zg, bb = zg * ht;
        if (PHASE == 1) { accz[mi][ni][r] = a; acch[mi][ni][r] = bb; }
        B = B * a + bb;
        A *= a;
      }
      *seg_ptr(segt, wr * 8 + mi * 4 + lg, d) = make_float2(A, B);
    }
  }
  __syncthreads();                           // SegT complete

  if (PHASE == 0) {
    if (tid < 256) {
      float PA = 1.f, PB = 0.f;
      #pragma unroll
      for (int s = 0; s < 16; s++) {
        float2 v = *seg_ptr(segt, s, tid);
        PB = v.x * PB + v.y;
        PA *= v.x;
      }
      Ap[(size_t)cb * 256 + tid] = PA;
      Bs[(size_t)cb * 256 + tid] = PB;
    }
    return;
  }

  // ---- PHASE 1: exclusive prefix over 16 segs ----
  if (tid < 256) {
    float PA = 1.f, PB = 0.f;
    #pragma unroll
    for (int s = 0; s < 16; s++) {
      float2* p = seg_ptr(segt, s, tid);
      float2 v = *p;
      *p = make_float2(PA, PB);
      PB = v.x * PB + v.y;
      PA *= v.x;
    }
  }
  __syncthreads();                           // exclusive prefixes ready

  // ---- read own prefixes + carry ----
  float ea[2][4], eb[2][4], h0v[4];
  #pragma unroll
  for (int ni = 0; ni < 4; ni++) {
    const int d = wc * 64 + ni * 16 + l15;
    h0v[ni] = carry[(size_t)cb * 256 + d];
    #pragma unroll
    for (int mi = 0; mi < 2; mi++) {
      float2 e = *seg_ptr(segt, wr * 8 + mi * 4 + lg, d);
      ea[mi][ni] = e.x; eb[mi][ni] = e.y;
    }
  }
  __syncthreads();                           // SegT reads done; As writable

  // ---- rebuild h1 tile into As (bf16 swizzled) ----
  #pragma unroll
  for (int ni = 0; ni < 4; ni++) {
    const int d = wc * 64 + ni * 16 + l15;
    char* sub = (char*)As + (d >> 6) * 8192;
    const int kl2 = (d & 63) * 2;
    #pragma unroll
    for (int mi = 0; mi < 2; mi++) {
      float h = ea[mi][ni] * h0v[ni] + eb[mi][ni];
      #pragma unroll
      for (int r = 0; r < 4; r++) {
        h = accz[mi][ni][r] * h + acch[mi][ni][r];
        const int t = wr * 32 + mi * 16 + lg * 4 + r;
        *(u16*)(sub + ((t * 128 + kl2) ^ ((t & 7) << 4))) = f2bf(h);
      }
    }
  }

  #pragma unroll
  for (int i = 0; i < 2; i++)
    #pragma unroll
    for (int j = 0; j < 4; j++) {
      f32x4 zz = {0.f, 0.f, 0.f, 0.f};
      accz[i][j] = zz; acch[i][j] = zz;
    }

  __syncthreads();                           // h-tile ready
  gemm_core_g(1, WtSb, As, wr, wc, l15, lg, accz, acch);
  __syncthreads();                           // As free for SegT

  // ---- layer-1 gates -> SegT -> totals -> Ap1/Bs1 ----
  #pragma unroll
  for (int ni = 0; ni < 4; ni++) {
    const int d = wc * 64 + ni * 16 + l15;
    const float bzv = bz1[d];
    const float bhv = bh1[d];
    #pragma unroll
    for (int mi = 0; mi < 2; mi++) {
      float A = 1.f, B = 0.f;
      #pragma unroll
      for (int r = 0; r < 4; r++) {
        float zl = accz[mi][ni][r] + bzv;
        float zg = 1.f / (1.f + __expf(-zl));
        float ht = acch[mi][ni][r] + bhv;
        float a = 1.f - zg, bb = zg * ht;
        B = B * a + bb;
        A *= a;
      }
      *seg_ptr(segt, wr * 8 + mi * 4 + lg, d) = make_float2(A, B);
    }
  }
  __syncthreads();
  if (tid < 256) {
    float PA = 1.f, PB = 0.f;
    #pragma unroll
    for (int s = 0; s < 16; s++) {
      float2 v = *seg_ptr(segt, s, tid);
      PB = v.x * PB + v.y;
      PA *= v.x;
    }
    Ap[(size_t)cb * 256 + tid] = PA;
    Bs[(size_t)cb * 256 + tid] = PB;
  }
}

// ---------- serial cross-chunk compose: carry per chunk ----------
__global__ void scan2_l0(const float* __restrict__ Ap0, const float* __restrict__ Bs0,
                         float* __restrict__ carry) {
  const int g = blockIdx.x * 256 + threadIdx.x;   // 8192 = 32 b * 256 d
  const int b = g >> 8, d = g & 255;
  float h = 0.f;
  for (int c = 0; c < NCH; c++) {
    const size_t idx = (size_t)(b * NCH + c) * 256 + d;
    carry[idx] = h;
    h = Bs0[idx] + Ap0[idx] * h;
  }
}

// ---------- layer-1 final: serial over chunk locals -> hlast ----------
__global__ void scan2_l1(const float* __restrict__ Ap1, const float* __restrict__ Bs1,
                         float* __restrict__ hlast) {
  const int g = blockIdx.x * 256 + threadIdx.x;   // 8192
  const int b = g >> 8, d = g & 255;
  float h = 0.f;
  for (int c = 0; c < NCH; c++) {
    const size_t idx = (size_t)(b * NCH + c) * 256 + d;
    h = Bs1[idx] + Ap1[idx] * h;
  }
  hlast[b * 256 + d] = h;
}

__global__ void cls_kernel(const float* __restrict__ hlast, const float* __restrict__ Wo,
                           const float* __restrict__ bo, float* __restrict__ out) {
  const int t = threadIdx.x;       // 256 = 32 b * 8 classes
  const int b = t >> 3, c = t & 7;
  float acc = bo[c];
  for (int d = 0; d < 256; d++) acc += hlast[b * 256 + d] * Wo[d * 8 + c];
  out[t] = acc;
}

extern "C" void kernel_launch(void* const* d_in, const int* in_sizes, int n_in,
                              void* d_out, int out_size, void* d_ws, size_t ws_size,
                              hipStream_t stream) {
  (void)in_sizes; (void)n_in; (void)out_size; (void)ws_size;
  const int*   x   = (const int*)d_in[0];
  const float* emb = (const float*)d_in[1];
  const float* Wz  = (const float*)d_in[2];
  const float* bz  = (const float*)d_in[3];
  const float* Wh  = (const float*)d_in[4];
  const float* bh  = (const float*)d_in[5];
  const float* Wo  = (const float*)d_in[6];
  const float* bo  = (const float*)d_in[7];
  float* out = (float*)d_out;
  char* ws = (char*)d_ws;

  // workspace (~38.3 MB; ws = 256 MiB)
  u16*   embq  = (u16*)  (ws);                      // 16,384,000 (pad to 16 MiB)
  u16*   WtS   = (u16*)  (ws + 16777216ull);        //    524,288
  float* Ap0   = (float*)(ws + 17301504ull);        //  4,194,304
  float* Bs0   = (float*)(ws + 21495808ull);        //  4,194,304
  float* carry = (float*)(ws + 25690112ull);        //  4,194,304
  float* Ap1   = (float*)(ws + 29884416ull);        //  4,194,304
  float* Bs1   = (float*)(ws + 34078720ull);        //  4,194,304
  float* hlast = (float*)(ws + 38273024ull);        //     32,768

  embq_kernel<<<8000, 256, 0, stream>>>(emb, embq);
  wt_kernel<<<1024, 256, 0, stream>>>(Wz, Wh, WtS);

  gru_kernel<0><<<NBLK, 512, 0, stream>>>(
      x, embq, WtS, bz, bh, bz + 256, bh + 256, nullptr, Ap0, Bs0);
  scan2_l0<<<32, 256, 0, stream>>>(Ap0, Bs0, carry);
  gru_kernel<1><<<NBLK, 512, 0, stream>>>(
      x, embq, WtS, bz, bh, bz + 256, bh + 256, carry, Ap1, Bs1);

  scan2_l1<<<32, 256, 0, stream>>>(Ap1, Bs1, hlast);
  cls_kernel<<<1, 256, 0, stream>>>(hlast, Wo, bo, out);
}

// Round 13
// 325.236 us; speedup vs baseline: 1.7303x; 1.7303x over previous
//
#include <hip/hip_runtime.h>
#include <stdint.h>

#define SEQ 8192
#define CS 64                       // chunk length == block row tile
#define NCH 128                     // chunks per sequence
#define NBLK 4096                   // 32 batches * 128 chunks

typedef float f32x4 __attribute__((ext_vector_type(4)));
typedef short short8 __attribute__((ext_vector_type(8)));
typedef unsigned short u16;
typedef u16 ushort8 __attribute__((ext_vector_type(8)));
typedef u16 ushort4v __attribute__((ext_vector_type(4)));

__device__ __forceinline__ u16 f2bf(float f) {
  uint32_t u = __float_as_uint(f);
  u += 0x7fffu + ((u >> 16) & 1u);   // round-to-nearest-even
  return (u16)(u >> 16);
}

// async 16B global->LDS (lds dest wave-uniform base; HW adds lane*16)
__device__ __forceinline__ void gld16(void* lds, const void* g) {
  __builtin_amdgcn_global_load_lds(
      (const __attribute__((address_space(1))) uint32_t*)g,
      (__attribute__((address_space(3))) uint32_t*)lds, 16, 0, 0);
}

// ---------- emb f32 -> bf16 table (one-time) ----------
__global__ void embq_kernel(const float* __restrict__ emb, u16* __restrict__ embq) {
  int i = (blockIdx.x * 256 + threadIdx.x) * 4;   // 8,192,000 elements exactly
  float4 v = *(const float4*)(emb + i);
  ushort4v p;
  p[0] = f2bf(v.x); p[1] = f2bf(v.y); p[2] = f2bf(v.z); p[3] = f2bf(v.w);
  *(ushort4v*)(embq + i) = p;
}

// ---------- weight preprocess: f32 [l][k][d] -> bf16 swizzled 4KB BK=32 tiles ----------
// WtS: 128 tiles of 4096 BYTES, tile index (mat*4 + dh)*8 + k32, in-tile [64 dloc][32 kl],
// byte = dloc*64 + ((kl*2) ^ (((dloc>>1)&3)<<4)).  mat: 0=Wz l0,1=Wz l1,2=Wh l0,3=Wh l1
__global__ void wt_kernel(const float* __restrict__ Wz, const float* __restrict__ Wh,
                          u16* __restrict__ WtS) {
  int idx = blockIdx.x * 256 + threadIdx.x;   // 4*65536
  int d = idx & 255;
  int k = (idx >> 8) & 255;
  int m = idx >> 16;
  const float* src = (m < 2 ? Wz : Wh) + (size_t)(m & 1) * 65536;
  float v = src[k * 256 + d];
  int dh = d >> 6, dloc = d & 63, k32 = k >> 5, kl = k & 31;
  size_t tile = ((size_t)(m * 4 + dh) * 8 + k32) * 4096;   // BYTES
  size_t byte = (size_t)(dloc * 64 + ((kl * 2) ^ (((dloc >> 1) & 3) << 4)));
  *(u16*)((char*)WtS + tile + byte) = f2bf(v);
}

// ---- stage one mat's k32 tile set (16KB = 4 dh-tiles of 4KB); wave w stages 2KB ----
__device__ __forceinline__ void stage32(char* dst, const char* WtSb, int mat, int k32,
                                        int w, int lane) {
  const int dh = w >> 1, half = w & 1;
  const char* src = WtSb + ((size_t)((mat * 4 + dh) * 8 + k32)) * 4096 + half * 2048 + lane * 16;
  char* d = dst + dh * 4096 + half * 2048;
  gld16(d, src);
  gld16(d + 1024, src + 1024);
}

// ---- one 32-k MFMA step (8 MFMAs/wave) from a 16KB B buffer ----
__device__ __forceinline__ void mfma_step(const char* P, const u16* As, int k32,
    int wr, int wc, int l15, int lg, f32x4 (&acc)[2][4])
{
  const int xm = (l15 & 7) << 4;
  const int kt = k32 >> 1, ks = k32 & 1;
  short8 fa[2];
  #pragma unroll
  for (int mi = 0; mi < 2; mi++)
    fa[mi] = *(const short8*)((const char*)As + kt * 8192 +
               (((wr * 32 + mi * 16 + l15) * 128 + ks * 64 + lg * 16) ^ xm));
  #pragma unroll
  for (int ni = 0; ni < 4; ni++) {
    const int dloc = ni * 16 + l15;
    const int off = dloc * 64 + ((lg * 16) ^ (((dloc >> 1) & 3) << 4));
    short8 fb = *(const short8*)(P + wc * 4096 + off);
    #pragma unroll
    for (int mi = 0; mi < 2; mi++)
      acc[mi][ni] = __builtin_amdgcn_mfma_f32_16x16x32_bf16(fa[mi], fb, acc[mi][ni], 0, 0, 0);
  }
}

// ---- software-pipelined GEMM: z in P0, h in P1; stage(s+1) issued before compute(s) ----
__device__ __forceinline__ void gemm_pipe(int lsel, const char* WtSb, const u16* As,
    char* P0, char* P1, int w, int wr, int wc, int l15, int lg, int lane,
    f32x4 (&accz)[2][4], f32x4 (&acch)[2][4])
{
  stage32(P0, WtSb, lsel, 0, w, lane);          // z k32=0
  for (int k32 = 0; k32 < 8; k32++) {
    __syncthreads();                            // z tile k32 arrived (flew under prev compute)
    stage32(P1, WtSb, 2 + lsel, k32, w, lane);  // issue h k32
    mfma_step(P0, As, k32, wr, wc, l15, lg, accz);
    __syncthreads();                            // h tile k32 arrived
    if (k32 < 7) stage32(P0, WtSb, lsel, k32 + 1, w, lane);   // issue z k32+1
    mfma_step(P1, As, k32, wr, wc, l15, lg, acch);
  }
}

// SegT addressing (overlays As): seg row 2048B, XOR-swizzled by seg to spread banks
__device__ __forceinline__ float2* seg_ptr(char* segt, int s, int d) {
  return (float2*)(segt + s * 2048 + ((d * 8) ^ (s << 4)));
}

// ---------- unified GEMM kernel ----------
// Block: 512 threads (8 waves: wr=w>>2 rows, wc=w&3 cols), 64 rows x 256 d, K=256.
// PHASE 0: gemm0 -> chunk-local (A,B) totals -> Ap0/Bs0.
// PHASE 1: gemm0 recompute (a,b in regs) + carry -> rebuild h1 in LDS -> gemm1 -> Ap1/Bs1.
template<int PHASE>
__global__ __launch_bounds__(512, 4)
void gru_kernel(const int* __restrict__ x, const u16* __restrict__ embq,
                const u16* __restrict__ WtS,
                const float* __restrict__ bz0, const float* __restrict__ bh0,
                const float* __restrict__ bz1, const float* __restrict__ bh1,
                const float* __restrict__ carry,
                float* __restrict__ Ap, float* __restrict__ Bs)
{
  __shared__ __align__(16) u16 As[16384];    // 32KB: 4 kt-subtiles [64t][64k] swz; SegT overlay
  __shared__ __align__(16) char P0[16384];   // 16KB: z-mat k32 tile (4 dh x 4KB)
  __shared__ __align__(16) char P1[16384];   // 16KB: h-mat k32 tile

  const int tid = threadIdx.x;
  const int lane = tid & 63;
  const int w = tid >> 6;
  const int wr = w >> 2, wc = w & 3;         // 2 row-groups x 4 col-groups
  const int l15 = lane & 15, lg = lane >> 4;
  const int cb = blockIdx.x;
  const int b = cb >> 7, c = cb & (NCH - 1);
  const char* WtSb = (const char*)WtS;
  char* segt = (char*)As;

  // ---- A gather: 64 rows x 256 k; thread = (row sm=tid>>3, 32-k chunk kq=tid&7) ----
  {
    const int sm = tid >> 3, kq = tid & 7;
    const int tok = x[b * SEQ + c * CS + sm];
    const u16* src = embq + (size_t)tok * 256 + kq * 32;
    char* sub = (char*)As + (kq >> 1) * 8192;
    const int kb = (kq & 1) * 64;
    const int swz = (sm & 7) << 4;
    #pragma unroll
    for (int j = 0; j < 4; j++) {
      ushort8 p = *(const ushort8*)(src + j * 8);
      *(ushort8*)(sub + ((sm * 128 + kb + j * 16) ^ swz)) = p;
    }
  }

  f32x4 accz[2][4], acch[2][4];
  #pragma unroll
  for (int i = 0; i < 2; i++)
    #pragma unroll
    for (int j = 0; j < 4; j++) {
      f32x4 zz = {0.f, 0.f, 0.f, 0.f};
      accz[i][j] = zz; acch[i][j] = zz;
    }

  __syncthreads();                           // As ready
  gemm_pipe(0, WtSb, As, P0, P1, w, wr, wc, l15, lg, lane, accz, acch);
  __syncthreads();                           // all MFMA done; As free for SegT

  // ---- layer-0 gates -> SegT (PHASE1 keeps a,b in regs) ----
  #pragma unroll
  for (int ni = 0; ni < 4; ni++) {
    const int d = wc * 64 + ni * 16 + l15;
    const float bzv = bz0[d];
    const float bhv = bh0[d];
    #pragma unroll
    for (int mi = 0; mi < 2; mi++) {
      float A = 1.f, B = 0.f;
      #pragma unroll
      for (int r = 0; r < 4; r++) {
        float zl = accz[mi][ni][r] + bzv;
        float a = __builtin_amdgcn_rcpf(1.f + __expf(zl));   // 1 - sigmoid(zl)
        float ht = acch[mi][ni][r] + bhv;
        float bb = (1.f - a) * ht;
        if (PHASE == 1) { accz[mi][ni][r] = a; acch[mi][ni][r] = bb; }
        B = B * a + bb;
        A *= a;
      }
      *seg_ptr(segt, wr * 8 + mi * 4 + lg, d) = make_float2(A, B);
    }
  }
  __syncthreads();                           // SegT complete

  if (PHASE == 0) {
    if (tid < 256) {
      float PA = 1.f, PB = 0.f;
      #pragma unroll
      for (int s = 0; s < 16; s++) {
        float2 v = *seg_ptr(segt, s, tid);
        PB = v.x * PB + v.y;
        PA *= v.x;
      }
      Ap[(size_t)cb * 256 + tid] = PA;
      Bs[(size_t)cb * 256 + tid] = PB;
    }
    return;
  }

  // ---- PHASE 1: exclusive prefix over 16 segs ----
  if (tid < 256) {
    float PA = 1.f, PB = 0.f;
    #pragma unroll
    for (int s = 0; s < 16; s++) {
      float2* p = seg_ptr(segt, s, tid);
      float2 v = *p;
      *p = make_float2(PA, PB);
      PB = v.x * PB + v.y;
      PA *= v.x;
    }
  }
  __syncthreads();                           // exclusive prefixes ready

  // ---- read own prefixes + carry ----
  float ea[2][4], eb[2][4], h0v[4];
  #pragma unroll
  for (int ni = 0; ni < 4; ni++) {
    const int d = wc * 64 + ni * 16 + l15;
    h0v[ni] = carry[(size_t)cb * 256 + d];
    #pragma unroll
    for (int mi = 0; mi < 2; mi++) {
      float2 e = *seg_ptr(segt, wr * 8 + mi * 4 + lg, d);
      ea[mi][ni] = e.x; eb[mi][ni] = e.y;
    }
  }
  __syncthreads();                           // SegT reads done; As writable

  // ---- rebuild h1 tile into As (bf16 swizzled) ----
  #pragma unroll
  for (int ni = 0; ni < 4; ni++) {
    const int d = wc * 64 + ni * 16 + l15;
    char* sub = (char*)As + (d >> 6) * 8192;
    const int kl2 = (d & 63) * 2;
    #pragma unroll
    for (int mi = 0; mi < 2; mi++) {
      float h = ea[mi][ni] * h0v[ni] + eb[mi][ni];
      #pragma unroll
      for (int r = 0; r < 4; r++) {
        h = accz[mi][ni][r] * h + acch[mi][ni][r];
        const int t = wr * 32 + mi * 16 + lg * 4 + r;
        *(u16*)(sub + ((t * 128 + kl2) ^ ((t & 7) << 4))) = f2bf(h);
      }
    }
  }

  #pragma unroll
  for (int i = 0; i < 2; i++)
    #pragma unroll
    for (int j = 0; j < 4; j++) {
      f32x4 zz = {0.f, 0.f, 0.f, 0.f};
      accz[i][j] = zz; acch[i][j] = zz;
    }

  __syncthreads();                           // h-tile ready
  gemm_pipe(1, WtSb, As, P0, P1, w, wr, wc, l15, lg, lane, accz, acch);
  __syncthreads();                           // As free for SegT

  // ---- layer-1 gates -> SegT -> totals -> Ap1/Bs1 ----
  #pragma unroll
  for (int ni = 0; ni < 4; ni++) {
    const int d = wc * 64 + ni * 16 + l15;
    const float bzv = bz1[d];
    const float bhv = bh1[d];
    #pragma unroll
    for (int mi = 0; mi < 2; mi++) {
      float A = 1.f, B = 0.f;
      #pragma unroll
      for (int r = 0; r < 4; r++) {
        float zl = accz[mi][ni][r] + bzv;
        float a = __builtin_amdgcn_rcpf(1.f + __expf(zl));
        float ht = acch[mi][ni][r] + bhv;
        float bb = (1.f - a) * ht;
        B = B * a + bb;
        A *= a;
      }
      *seg_ptr(segt, wr * 8 + mi * 4 + lg, d) = make_float2(A, B);
    }
  }
  __syncthreads();
  if (tid < 256) {
    float PA = 1.f, PB = 0.f;
    #pragma unroll
    for (int s = 0; s < 16; s++) {
      float2 v = *seg_ptr(segt, s, tid);
      PB = v.x * PB + v.y;
      PA *= v.x;
    }
    Ap[(size_t)cb * 256 + tid] = PA;
    Bs[(size_t)cb * 256 + tid] = PB;
  }
}

// ---------- serial cross-chunk compose: carry per chunk ----------
__global__ void scan2_l0(const float* __restrict__ Ap0, const float* __restrict__ Bs0,
                         float* __restrict__ carry) {
  const int g = blockIdx.x * 256 + threadIdx.x;   // 8192 = 32 b * 256 d
  const int b = g >> 8, d = g & 255;
  float h = 0.f;
  for (int c = 0; c < NCH; c++) {
    const size_t idx = (size_t)(b * NCH + c) * 256 + d;
    carry[idx] = h;
    h = Bs0[idx] + Ap0[idx] * h;
  }
}

// ---------- layer-1 final: serial over chunk locals -> hlast ----------
__global__ void scan2_l1(const float* __restrict__ Ap1, const float* __restrict__ Bs1,
                         float* __restrict__ hlast) {
  const int g = blockIdx.x * 256 + threadIdx.x;   // 8192
  const int b = g >> 8, d = g & 255;
  float h = 0.f;
  for (int c = 0; c < NCH; c++) {
    const size_t idx = (size_t)(b * NCH + c) * 256 + d;
    h = Bs1[idx] + Ap1[idx] * h;
  }
  hlast[b * 256 + d] = h;
}

__global__ void cls_kernel(const float* __restrict__ hlast, const float* __restrict__ Wo,
                           const float* __restrict__ bo, float* __restrict__ out) {
  const int t = threadIdx.x;       // 256 = 32 b * 8 classes
  const int b = t >> 3, c = t & 7;
  float acc = bo[c];
  for (int d = 0; d < 256; d++) acc += hlast[b * 256 + d] * Wo[d * 8 + c];
  out[t] = acc;
}

extern "C" void kernel_launch(void* const* d_in, const int* in_sizes, int n_in,
                              void* d_out, int out_size, void* d_ws, size_t ws_size,
                              hipStream_t stream) {
  (void)in_sizes; (void)n_in; (void)out_size; (void)ws_size;
  const int*   x   = (const int*)d_in[0];
  const float* emb = (const float*)d_in[1];
  const float* Wz  = (const float*)d_in[2];
  const float* bz  = (const float*)d_in[3];
  const float* Wh  = (const float*)d_in[4];
  const float* bh  = (const float*)d_in[5];
  const float* Wo  = (const float*)d_in[6];
  const float* bo  = (const float*)d_in[7];
  float* out = (float*)d_out;
  char* ws = (char*)d_ws;

  // workspace (~38.3 MB; ws = 256 MiB)
  u16*   embq  = (u16*)  (ws);                      // 16,384,000 (pad to 16 MiB)
  u16*   WtS   = (u16*)  (ws + 16777216ull);        //    524,288
  float* Ap0   = (float*)(ws + 17301504ull);        //  4,194,304
  float* Bs0   = (float*)(ws + 21495808ull);        //  4,194,304
  float* carry = (float*)(ws + 25690112ull);        //  4,194,304
  float* Ap1   = (float*)(ws + 29884416ull);        //  4,194,304
  float* Bs1   = (float*)(ws + 34078720ull);        //  4,194,304
  float* hlast = (float*)(ws + 38273024ull);        //     32,768

  embq_kernel<<<8000, 256, 0, stream>>>(emb, embq);
  wt_kernel<<<1024, 256, 0, stream>>>(Wz, Wh, WtS);

  gru_kernel<0><<<NBLK, 512, 0, stream>>>(
      x, embq, WtS, bz, bh, bz + 256, bh + 256, nullptr, Ap0, Bs0);
  scan2_l0<<<32, 256, 0, stream>>>(Ap0, Bs0, carry);
  gru_kernel<1><<<NBLK, 512, 0, stream>>>(
      x, embq, WtS, bz, bh, bz + 256, bh + 256, carry, Ap1, Bs1);

  scan2_l1<<<32, 256, 0, stream>>>(Ap1, Bs1, hlast);
  cls_kernel<<<1, 256, 0, stream>>>(hlast, Wo, bo, out);
}

// Round 15
// 311.844 us; speedup vs baseline: 1.8046x; 1.0429x over previous
//
#include <hip/hip_runtime.h>
#include <stdint.h>

#define SEQ 8192
#define CS 64                       // chunk length == block row tile
#define NCH 128                     // chunks per sequence
#define NBLK 4096                   // 32 batches * 128 chunks

typedef float f32x4 __attribute__((ext_vector_type(4)));
typedef short short8 __attribute__((ext_vector_type(8)));
typedef unsigned short u16;
typedef u16 ushort8 __attribute__((ext_vector_type(8)));
typedef u16 ushort4v __attribute__((ext_vector_type(4)));

__device__ __forceinline__ u16 f2bf(float f) {
  uint32_t u = __float_as_uint(f);
  u += 0x7fffu + ((u >> 16) & 1u);   // round-to-nearest-even
  return (u16)(u >> 16);
}

// async 16B global->LDS (lds dest wave-uniform base; HW adds lane*16)
__device__ __forceinline__ void gld16(void* lds, const void* g) {
  __builtin_amdgcn_global_load_lds(
      (const __attribute__((address_space(1))) uint32_t*)g,
      (__attribute__((address_space(3))) uint32_t*)lds, 16, 0, 0);
}

// ---------- emb f32 -> bf16 table (one-time) ----------
__global__ void embq_kernel(const float* __restrict__ emb, u16* __restrict__ embq) {
  int i = (blockIdx.x * 256 + threadIdx.x) * 4;   // 8,192,000 elements exactly
  float4 v = *(const float4*)(emb + i);
  ushort4v p;
  p[0] = f2bf(v.x); p[1] = f2bf(v.y); p[2] = f2bf(v.z); p[3] = f2bf(v.w);
  *(ushort4v*)(embq + i) = p;
}

// ---------- weight preprocess: f32 [l][k][d] -> bf16 swizzled 4KB BK=32 tiles ----------
// WtS: 128 tiles of 4096 BYTES, tile index (mat*4 + dh)*8 + k32, in-tile [64 dloc][32 kl],
// byte = dloc*64 + ((kl*2) ^ (((dloc>>1)&3)<<4)).  mat: 0=Wz l0,1=Wz l1,2=Wh l0,3=Wh l1
__global__ void wt_kernel(const float* __restrict__ Wz, const float* __restrict__ Wh,
                          u16* __restrict__ WtS) {
  int idx = blockIdx.x * 256 + threadIdx.x;   // 4*65536
  int d = idx & 255;
  int k = (idx >> 8) & 255;
  int m = idx >> 16;
  const float* src = (m < 2 ? Wz : Wh) + (size_t)(m & 1) * 65536;
  float v = src[k * 256 + d];
  int dh = d >> 6, dloc = d & 63, k32 = k >> 5, kl = k & 31;
  size_t tile = ((size_t)(m * 4 + dh) * 8 + k32) * 4096;   // BYTES
  size_t byte = (size_t)(dloc * 64 + ((kl * 2) ^ (((dloc >> 1) & 3) << 4)));
  *(u16*)((char*)WtS + tile + byte) = f2bf(v);
}

// ---- stage one mat's k32 tile set (16KB = 4 dh-tiles of 4KB); wave w stages 2KB ----
__device__ __forceinline__ void stage32(char* dst, const char* WtSb, int mat, int k32,
                                        int w, int lane) {
  const int dh = w >> 1, half = w & 1;
  const char* src = WtSb + ((size_t)((mat * 4 + dh) * 8 + k32)) * 4096 + half * 2048 + lane * 16;
  char* d = dst + dh * 4096 + half * 2048;
  gld16(d, src);
  gld16(d + 1024, src + 1024);
}

// ---- one 32-k MFMA step (8 MFMAs/wave) from a 16KB B buffer ----
__device__ __forceinline__ void mfma_step(const char* P, const u16* As, int k32,
    int wr, int wc, int l15, int lg, f32x4 (&acc)[2][4])
{
  const int xm = (l15 & 7) << 4;
  const int kt = k32 >> 1, ks = k32 & 1;
  short8 fa[2];
  #pragma unroll
  for (int mi = 0; mi < 2; mi++)
    fa[mi] = *(const short8*)((const char*)As + kt * 8192 +
               (((wr * 32 + mi * 16 + l15) * 128 + ks * 64 + lg * 16) ^ xm));
  #pragma unroll
  for (int ni = 0; ni < 4; ni++) {
    const int dloc = ni * 16 + l15;
    const int off = dloc * 64 + ((lg * 16) ^ (((dloc >> 1) & 3) << 4));
    short8 fb = *(const short8*)(P + wc * 4096 + off);
    #pragma unroll
    for (int mi = 0; mi < 2; mi++)
      acc[mi][ni] = __builtin_amdgcn_mfma_f32_16x16x32_bf16(fa[mi], fb, acc[mi][ni], 0, 0, 0);
  }
}

// ---- tri-buffered counted-vmcnt pipeline (T3/T4): 2 stages in flight across raw barriers ----
// 16 stages j=0..15: mat = z if j even else h; k32 = j>>1 (0..7); buffer j%3.
// Per wave, one stage = 2 gld16. Iteration i computes stage i after vmcnt proves it landed.
__device__ __forceinline__ void gemm_pipe3(int lsel, const char* WtSb, const u16* As,
    char* Pb, int w, int wr, int wc, int l15, int lg, int lane,
    f32x4 (&accz)[2][4], f32x4 (&acch)[2][4])
{
  stage32(Pb,         WtSb, lsel,     0, w, lane);   // j=0 (z, k32=0) -> buf0
  stage32(Pb + 16384, WtSb, 2 + lsel, 0, w, lane);   // j=1 (h, k32=0) -> buf1
  int cur = 0, nx2 = 2;                              // i%3 and (i+2)%3
  for (int i = 0; i < 16; ++i) {
    // outstanding before wait = stages {i, i+1} = 4 loads -> vmcnt(2) proves stage(i) landed;
    // tail i=15: only stage 15 outstanding -> need vmcnt(0)
    if (i < 15) asm volatile("s_waitcnt vmcnt(2)" ::: "memory");
    else        asm volatile("s_waitcnt vmcnt(0)" ::: "memory");
    __builtin_amdgcn_s_barrier();                    // stage(i) in LDS everywhere;
    __builtin_amdgcn_sched_barrier(0);               // all waves done compute(i-1)
    if (i + 2 < 16) {
      const int j = i + 2;
      stage32(Pb + nx2 * 16384, WtSb, (j & 1) ? (2 + lsel) : lsel, j >> 1, w, lane);
    }
    if (i & 1) mfma_step(Pb + cur * 16384, As, i >> 1, wr, wc, l15, lg, acch);
    else       mfma_step(Pb + cur * 16384, As, i >> 1, wr, wc, l15, lg, accz);
    cur = (cur == 2) ? 0 : cur + 1;
    nx2 = (nx2 == 2) ? 0 : nx2 + 1;
  }
}

// SegT addressing (overlays As): seg row 2048B, XOR-swizzled by seg to spread banks
__device__ __forceinline__ float2* seg_ptr(char* segt, int s, int d) {
  return (float2*)(segt + s * 2048 + ((d * 8) ^ (s << 4)));
}

// ---------- unified GEMM kernel ----------
// Block: 512 threads (8 waves: wr=w>>2 rows, wc=w&3 cols), 64 rows x 256 d, K=256.
// PHASE 0: gemm0 -> chunk-local (A,B) totals -> Ap0/Bs0.
// PHASE 1: gemm0 recompute (a,b in regs) + carry -> rebuild h1 in LDS -> gemm1 -> Ap1/Bs1.
template<int PHASE>
__global__ __launch_bounds__(512, 4)
void gru_kernel(const int* __restrict__ x, const u16* __restrict__ embq,
                const u16* __restrict__ WtS,
                const float* __restrict__ bz0, const float* __restrict__ bh0,
                const float* __restrict__ bz1, const float* __restrict__ bh1,
                const float* __restrict__ carry,
                float* __restrict__ Ap, float* __restrict__ Bs)
{
  __shared__ __align__(16) u16 As[16384];    // 32KB: 4 kt-subtiles [64t][64k] swz; SegT overlay
  __shared__ __align__(16) char Pb[49152];   // 48KB: 3 x 16KB B buffers (tri-buffer)

  const int tid = threadIdx.x;
  const int lane = tid & 63;
  const int w = tid >> 6;
  const int wr = w >> 2, wc = w & 3;         // 2 row-groups x 4 col-groups
  const int l15 = lane & 15, lg = lane >> 4;
  const int cb = blockIdx.x;
  const int b = cb >> 7, c = cb & (NCH - 1);
  const char* WtSb = (const char*)WtS;
  char* segt = (char*)As;

  // ---- A gather: 64 rows x 256 k; thread = (row sm=tid>>3, 32-k chunk kq=tid&7) ----
  {
    const int sm = tid >> 3, kq = tid & 7;
    const int tok = x[b * SEQ + c * CS + sm];
    const u16* src = embq + (size_t)tok * 256 + kq * 32;
    char* sub = (char*)As + (kq >> 1) * 8192;
    const int kb = (kq & 1) * 64;
    const int swz = (sm & 7) << 4;
    #pragma unroll
    for (int j = 0; j < 4; j++) {
      ushort8 p = *(const ushort8*)(src + j * 8);
      *(ushort8*)(sub + ((sm * 128 + kb + j * 16) ^ swz)) = p;
    }
  }

  f32x4 accz[2][4], acch[2][4];
  #pragma unroll
  for (int i = 0; i < 2; i++)
    #pragma unroll
    for (int j = 0; j < 4; j++) {
      f32x4 zz = {0.f, 0.f, 0.f, 0.f};
      accz[i][j] = zz; acch[i][j] = zz;
    }

  __syncthreads();                           // As ready (full drain -> vmcnt 0 at pipe entry)
  gemm_pipe3(0, WtSb, As, Pb, w, wr, wc, l15, lg, lane, accz, acch);
  __syncthreads();                           // all MFMA done; As free for SegT

  // ---- layer-0 gates -> SegT (PHASE1 keeps a,b in regs) ----
  #pragma unroll
  for (int ni = 0; ni < 4; ni++) {
    const int d = wc * 64 + ni * 16 + l15;
    const float bzv = bz0[d];
    const float bhv = bh0[d];
    #pragma unroll
    for (int mi = 0; mi < 2; mi++) {
      float A = 1.f, B = 0.f;
      #pragma unroll
      for (int r = 0; r < 4; r++) {
        float zl = accz[mi][ni][r] + bzv;
        float a = __builtin_amdgcn_rcpf(1.f + __expf(zl));   // 1 - sigmoid(zl)
        float ht = acch[mi][ni][r] + bhv;
        float bb = (1.f - a) * ht;
        if (PHASE == 1) { accz[mi][ni][r] = a; acch[mi][ni][r] = bb; }
        B = B * a + bb;
        A *= a;
      }
      *seg_ptr(segt, wr * 8 + mi * 4 + lg, d) = make_float2(A, B);
    }
  }
  __syncthreads();                           // SegT complete

  if (PHASE == 0) {
    if (tid < 256) {
      float PA = 1.f, PB = 0.f;
      #pragma unroll
      for (int s = 0; s < 16; s++) {
        float2 v = *seg_ptr(segt, s, tid);
        PB = v.x * PB + v.y;
        PA *= v.x;
      }
      Ap[(size_t)cb * 256 + tid] = PA;
      Bs[(size_t)cb * 256 + tid] = PB;
    }
    return;
  }

  // ---- PHASE 1: exclusive prefix over 16 segs ----
  if (tid < 256) {
    float PA = 1.f, PB = 0.f;
    #pragma unroll
    for (int s = 0; s < 16; s++) {
      float2* p = seg_ptr(segt, s, tid);
      float2 v = *p;
      *p = make_float2(PA, PB);
      PB = v.x * PB + v.y;
      PA *= v.x;
    }
  }
  __syncthreads();                           // exclusive prefixes ready

  // ---- read own prefixes + carry ----
  float ea[2][4], eb[2][4], h0v[4];
  #pragma unroll
  for (int ni = 0; ni < 4; ni++) {
    const int d = wc * 64 + ni * 16 + l15;
    h0v[ni] = carry[(size_t)cb * 256 + d];
    #pragma unroll
    for (int mi = 0; mi < 2; mi++) {
      float2 e = *seg_ptr(segt, wr * 8 + mi * 4 + lg, d);
      ea[mi][ni] = e.x; eb[mi][ni] = e.y;
    }
  }
  __syncthreads();                           // SegT reads done; As writable

  // ---- rebuild h1 tile into As (bf16 swizzled) ----
  #pragma unroll
  for (int ni = 0; ni < 4; ni++) {
    const int d = wc * 64 + ni * 16 + l15;
    char* sub = (char*)As + (d >> 6) * 8192;
    const int kl2 = (d & 63) * 2;
    #pragma unroll
    for (int mi = 0; mi < 2; mi++) {
      float h = ea[mi][ni] * h0v[ni] + eb[mi][ni];
      #pragma unroll
      for (int r = 0; r < 4; r++) {
        h = accz[mi][ni][r] * h + acch[mi][ni][r];
        const int t = wr * 32 + mi * 16 + lg * 4 + r;
        *(u16*)(sub + ((t * 128 + kl2) ^ ((t & 7) << 4))) = f2bf(h);
      }
    }
  }

  #pragma unroll
  for (int i = 0; i < 2; i++)
    #pragma unroll
    for (int j = 0; j < 4; j++) {
      f32x4 zz = {0.f, 0.f, 0.f, 0.f};
      accz[i][j] = zz; acch[i][j] = zz;
    }

  __syncthreads();                           // h-tile ready (full drain -> vmcnt 0)
  gemm_pipe3(1, WtSb, As, Pb, w, wr, wc, l15, lg, lane, accz, acch);
  __syncthreads();                           // As free for SegT

  // ---- layer-1 gates -> SegT -> totals -> Ap1/Bs1 ----
  #pragma unroll
  for (int ni = 0; ni < 4; ni++) {
    const int d = wc * 64 + ni * 16 + l15;
    const float bzv = bz1[d];
    const float bhv = bh1[d];
    #pragma unroll
    for (int mi = 0; mi < 2; mi++) {
      float A = 1.f, B = 0.f;
      #pragma unroll
      for (int r = 0; r < 4; r++) {
        float zl = accz[mi][ni][r] + bzv;
        float a = __builtin_amdgcn_rcpf(1.f + __expf(zl));
        float ht = acch[mi][ni][r] + bhv;
        float bb = (1.f - a) * ht;
        B = B * a + bb;
        A *= a;
      }
      *seg_ptr(segt, wr * 8 + mi * 4 + lg, d) = make_float2(A, B);
    }
  }
  __syncthreads();
  if (tid < 256) {
    float PA = 1.f, PB = 0.f;
    #pragma unroll
    for (int s = 0; s < 16; s++) {
      float2 v = *seg_ptr(segt, s, tid);
      PB = v.x * PB + v.y;
      PA *= v.x;
    }
    Ap[(size_t)cb * 256 + tid] = PA;
    Bs[(size_t)cb * 256 + tid] = PB;
  }
}

// ---------- serial cross-chunk compose: carry per chunk ----------
__global__ void scan2_l0(const float* __restrict__ Ap0, const float* __restrict__ Bs0,
                         float* __restrict__ carry) {
  const int g = blockIdx.x * 256 + threadIdx.x;   // 8192 = 32 b * 256 d
  const int b = g >> 8, d = g & 255;
  float h = 0.f;
  for (int c = 0; c < NCH; c++) {
    const size_t idx = (size_t)(b * NCH + c) * 256 + d;
    carry[idx] = h;
    h = Bs0[idx] + Ap0[idx] * h;
  }
}

// ---------- layer-1 final: serial over chunk locals -> hlast ----------
__global__ void scan2_l1(const float* __restrict__ Ap1, const float* __restrict__ Bs1,
                         float* __restrict__ hlast) {
  const int g = blockIdx.x * 256 + threadIdx.x;   // 8192
  const int b = g >> 8, d = g & 255;
  float h = 0.f;
  for (int c = 0; c < NCH; c++) {
    const size_t idx = (size_t)(b * NCH + c) * 256 + d;
    h = Bs1[idx] + Ap1[idx] * h;
  }
  hlast[b * 256 + d] = h;
}

__global__ void cls_kernel(const float* __restrict__ hlast, const float* __restrict__ Wo,
                           const float* __restrict__ bo, float* __restrict__ out) {
  const int t = threadIdx.x;       // 256 = 32 b * 8 classes
  const int b = t >> 3, c = t & 7;
  float acc = bo[c];
  for (int d = 0; d < 256; d++) acc += hlast[b * 256 + d] * Wo[d * 8 + c];
  out[t] = acc;
}

extern "C" void kernel_launch(void* const* d_in, const int* in_sizes, int n_in,
                              void* d_out, int out_size, void* d_ws, size_t ws_size,
                              hipStream_t stream) {
  (void)in_sizes; (void)n_in; (void)out_size; (void)ws_size;
  const int*   x   = (const int*)d_in[0];
  const float* emb = (const float*)d_in[1];
  const float* Wz  = (const float*)d_in[2];
  const float* bz  = (const float*)d_in[3];
  const float* Wh  = (const float*)d_in[4];
  const float* bh  = (const float*)d_in[5];
  const float* Wo  = (const float*)d_in[6];
  const float* bo  = (const float*)d_in[7];
  float* out = (float*)d_out;
  char* ws = (char*)d_ws;

  // workspace (~38.3 MB; ws = 256 MiB)
  u16*   embq  = (u16*)  (ws);                      // 16,384,000 (pad to 16 MiB)
  u16*   WtS   = (u16*)  (ws + 16777216ull);        //    524,288
  float* Ap0   = (float*)(ws + 17301504ull);        //  4,194,304
  float* Bs0   = (float*)(ws + 21495808ull);        //  4,194,304
  float* carry = (float*)(ws + 25690112ull);        //  4,194,304
  float* Ap1   = (float*)(ws + 29884416ull);        //  4,194,304
  float* Bs1   = (float*)(ws + 34078720ull);        //  4,194,304
  float* hlast = (float*)(ws + 38273024ull);        //     32,768

  embq_kernel<<<8000, 256, 0, stream>>>(emb, embq);
  wt_kernel<<<1024, 256, 0, stream>>>(Wz, Wh, WtS);

  gru_kernel<0><<<NBLK, 512, 0, stream>>>(
      x, embq, WtS, bz, bh, bz + 256, bh + 256, nullptr, Ap0, Bs0);
  scan2_l0<<<32, 256, 0, stream>>>(Ap0, Bs0, carry);
  gru_kernel<1><<<NBLK, 512, 0, stream>>>(
      x, embq, WtS, bz, bh, bz + 256, bh + 256, carry, Ap1, Bs1);

  scan2_l1<<<32, 256, 0, stream>>>(Ap1, Bs1, hlast);
  cls_kernel<<<1, 256, 0, stream>>>(hlast, Wo, bo, out);
}

// Round 16
// 311.573 us; speedup vs baseline: 1.8062x; 1.0009x over previous
//
#include <hip/hip_runtime.h>
#include <stdint.h>

#define SEQ 8192
#define CS 64                       // chunk length == block row tile
#define NCH 128                     // chunks per sequence
#define NBLK 4096                   // 32 batches * 128 chunks

typedef float f32x4 __attribute__((ext_vector_type(4)));
typedef short short8 __attribute__((ext_vector_type(8)));
typedef unsigned short u16;
typedef u16 ushort8 __attribute__((ext_vector_type(8)));
typedef u16 ushort4v __attribute__((ext_vector_type(4)));

__device__ __forceinline__ u16 f2bf(float f) {
  uint32_t u = __float_as_uint(f);
  u += 0x7fffu + ((u >> 16) & 1u);   // round-to-nearest-even
  return (u16)(u >> 16);
}

// async 16B global->LDS (lds dest wave-uniform base; HW adds lane*16)
__device__ __forceinline__ void gld16(void* lds, const void* g) {
  __builtin_amdgcn_global_load_lds(
      (const __attribute__((address_space(1))) uint32_t*)g,
      (__attribute__((address_space(3))) uint32_t*)lds, 16, 0, 0);
}

// ---------- emb f32 -> bf16 table (one-time) ----------
__global__ void embq_kernel(const float* __restrict__ emb, u16* __restrict__ embq) {
  int i = (blockIdx.x * 256 + threadIdx.x) * 4;   // 8,192,000 elements exactly
  float4 v = *(const float4*)(emb + i);
  ushort4v p;
  p[0] = f2bf(v.x); p[1] = f2bf(v.y); p[2] = f2bf(v.z); p[3] = f2bf(v.w);
  *(ushort4v*)(embq + i) = p;
}

// ---------- weight preprocess: f32 [l][k][d] -> bf16 swizzled 4KB BK=32 tiles ----------
// WtS: 128 tiles of 4096 BYTES, tile index (mat*4 + dh)*8 + k32, in-tile [64 dloc][32 kl],
// byte = dloc*64 + ((kl*2) ^ (((dloc>>1)&3)<<4)).  mat: 0=Wz l0,1=Wz l1,2=Wh l0,3=Wh l1
__global__ void wt_kernel(const float* __restrict__ Wz, const float* __restrict__ Wh,
                          u16* __restrict__ WtS) {
  int idx = blockIdx.x * 256 + threadIdx.x;   // 4*65536
  int d = idx & 255;
  int k = (idx >> 8) & 255;
  int m = idx >> 16;
  const float* src = (m < 2 ? Wz : Wh) + (size_t)(m & 1) * 65536;
  float v = src[k * 256 + d];
  int dh = d >> 6, dloc = d & 63, k32 = k >> 5, kl = k & 31;
  size_t tile = ((size_t)(m * 4 + dh) * 8 + k32) * 4096;   // BYTES
  size_t byte = (size_t)(dloc * 64 + ((kl * 2) ^ (((dloc >> 1) & 3) << 4)));
  *(u16*)((char*)WtS + tile + byte) = f2bf(v);
}

// ---- stage one mat's k32 tile set (16KB = 4 dh-tiles of 4KB); wave w stages 2KB ----
__device__ __forceinline__ void stage32(char* dst, const char* WtSb, int mat, int k32,
                                        int w, int lane) {
  const int dh = w >> 1, half = w & 1;
  const char* src = WtSb + ((size_t)((mat * 4 + dh) * 8 + k32)) * 4096 + half * 2048 + lane * 16;
  char* d = dst + dh * 4096 + half * 2048;
  gld16(d, src);
  gld16(d + 1024, src + 1024);
}

// ---- A-fragment load for one k32 (shared by the z and h steps of that k32) ----
__device__ __forceinline__ void load_fa(const u16* As, int k32, int wr, int l15, int lg,
                                        short8 (&fa)[2]) {
  const int xm = (l15 & 7) << 4;
  const int kt = k32 >> 1, ks = k32 & 1;
  #pragma unroll
  for (int mi = 0; mi < 2; mi++)
    fa[mi] = *(const short8*)((const char*)As + kt * 8192 +
               (((wr * 32 + mi * 16 + l15) * 128 + ks * 64 + lg * 16) ^ xm));
}

// ---- one 32-k MFMA step (8 MFMAs/wave) from a 16KB B buffer, fa provided ----
__device__ __forceinline__ void mfma_frags(const char* P, const short8 (&fa)[2],
    int wc, int l15, int lg, f32x4 (&acc)[2][4])
{
  #pragma unroll
  for (int ni = 0; ni < 4; ni++) {
    const int dloc = ni * 16 + l15;
    const int off = dloc * 64 + ((lg * 16) ^ (((dloc >> 1) & 3) << 4));
    short8 fb = *(const short8*)(P + wc * 4096 + off);
    #pragma unroll
    for (int mi = 0; mi < 2; mi++)
      acc[mi][ni] = __builtin_amdgcn_mfma_f32_16x16x32_bf16(fa[mi], fb, acc[mi][ni], 0, 0, 0);
  }
}

// ---- tri-buffered counted-vmcnt pipeline (T3/T4): 2 stages in flight across raw barriers ----
// 16 stages j=0..15: mat = z if j even else h; k32 = j>>1 (0..7); buffer j%3.
// Fully unrolled: buffer indices and swizzle offsets fold to immediates.
// fa loaded on even steps only (z), reused by the h step of the same k32.
__device__ __forceinline__ void gemm_pipe3(int lsel, const char* WtSb, const u16* As,
    char* Pb, int w, int wr, int wc, int l15, int lg, int lane,
    f32x4 (&accz)[2][4], f32x4 (&acch)[2][4])
{
  stage32(Pb,         WtSb, lsel,     0, w, lane);   // j=0 (z, k32=0) -> buf0
  stage32(Pb + 16384, WtSb, 2 + lsel, 0, w, lane);   // j=1 (h, k32=0) -> buf1
  short8 fa[2];
  #pragma unroll
  for (int i = 0; i < 16; ++i) {
    // outstanding before wait = stages {i, i+1} = 4 loads -> vmcnt(2) proves stage(i) landed;
    // tail i=15: only stage 15 outstanding -> vmcnt(0)
    if (i < 15) asm volatile("s_waitcnt vmcnt(2)" ::: "memory");
    else        asm volatile("s_waitcnt vmcnt(0)" ::: "memory");
    __builtin_amdgcn_s_barrier();                    // stage(i) in LDS everywhere;
    __builtin_amdgcn_sched_barrier(0);               // all waves done compute(i-1)
    if (i + 2 < 16)
      stage32(Pb + ((i + 2) % 3) * 16384, WtSb,
              ((i + 2) & 1) ? (2 + lsel) : lsel, (i + 2) >> 1, w, lane);
    if ((i & 1) == 0) {
      load_fa(As, i >> 1, wr, l15, lg, fa);
      mfma_frags(Pb + (i % 3) * 16384, fa, wc, l15, lg, accz);
    } else {
      mfma_frags(Pb + (i % 3) * 16384, fa, wc, l15, lg, acch);
    }
  }
}

// SegT addressing (overlays As): seg row 2048B, XOR-swizzled by seg to spread banks
__device__ __forceinline__ float2* seg_ptr(char* segt, int s, int d) {
  return (float2*)(segt + s * 2048 + ((d * 8) ^ (s << 4)));
}

// ---------- unified GEMM kernel ----------
// Block: 512 threads (8 waves: wr=w>>2 rows, wc=w&3 cols), 64 rows x 256 d, K=256.
// PHASE 0: gemm0 -> chunk-local (A,B) totals -> Ap0/Bs0.
// PHASE 1: gemm0 recompute (a,b in regs) + carry -> rebuild h1 in LDS -> gemm1 -> Ap1/Bs1.
template<int PHASE>
__global__ __launch_bounds__(512, 4)
void gru_kernel(const int* __restrict__ x, const u16* __restrict__ embq,
                const u16* __restrict__ WtS,
                const float* __restrict__ bz0, const float* __restrict__ bh0,
                const float* __restrict__ bz1, const float* __restrict__ bh1,
                const float* __restrict__ carry,
                float* __restrict__ Ap, float* __restrict__ Bs)
{
  __shared__ __align__(16) u16 As[16384];    // 32KB: 4 kt-subtiles [64t][64k] swz; SegT overlay
  __shared__ __align__(16) char Pb[49152];   // 48KB: 3 x 16KB B buffers (tri-buffer)

  const int tid = threadIdx.x;
  const int lane = tid & 63;
  const int w = tid >> 6;
  const int wr = w >> 2, wc = w & 3;         // 2 row-groups x 4 col-groups
  const int l15 = lane & 15, lg = lane >> 4;
  const int cb = blockIdx.x;
  const int b = cb >> 7, c = cb & (NCH - 1);
  const char* WtSb = (const char*)WtS;
  char* segt = (char*)As;

  // ---- A gather: 64 rows x 256 k; thread = (row sm=tid>>3, 32-k chunk kq=tid&7) ----
  {
    const int sm = tid >> 3, kq = tid & 7;
    const int tok = x[b * SEQ + c * CS + sm];
    const u16* src = embq + (size_t)tok * 256 + kq * 32;
    char* sub = (char*)As + (kq >> 1) * 8192;
    const int kb = (kq & 1) * 64;
    const int swz = (sm & 7) << 4;
    #pragma unroll
    for (int j = 0; j < 4; j++) {
      ushort8 p = *(const ushort8*)(src + j * 8);
      *(ushort8*)(sub + ((sm * 128 + kb + j * 16) ^ swz)) = p;
    }
  }

  f32x4 accz[2][4], acch[2][4];
  #pragma unroll
  for (int i = 0; i < 2; i++)
    #pragma unroll
    for (int j = 0; j < 4; j++) {
      f32x4 zz = {0.f, 0.f, 0.f, 0.f};
      accz[i][j] = zz; acch[i][j] = zz;
    }

  __syncthreads();                           // As ready (full drain -> vmcnt 0 at pipe entry)
  gemm_pipe3(0, WtSb, As, Pb, w, wr, wc, l15, lg, lane, accz, acch);
  __syncthreads();                           // all MFMA done; As free for SegT

  // ---- layer-0 gates -> SegT (PHASE1 keeps a,b in regs) ----
  #pragma unroll
  for (int ni = 0; ni < 4; ni++) {
    const int d = wc * 64 + ni * 16 + l15;
    const float bzv = bz0[d];
    const float bhv = bh0[d];
    #pragma unroll
    for (int mi = 0; mi < 2; mi++) {
      float A = 1.f, B = 0.f;
      #pragma unroll
      for (int r = 0; r < 4; r++) {
        float zl = accz[mi][ni][r] + bzv;
        float a = __builtin_amdgcn_rcpf(1.f + __expf(zl));   // 1 - sigmoid(zl)
        float ht = acch[mi][ni][r] + bhv;
        float bb = (1.f - a) * ht;
        if (PHASE == 1) { accz[mi][ni][r] = a; acch[mi][ni][r] = bb; }
        B = B * a + bb;
        A *= a;
      }
      *seg_ptr(segt, wr * 8 + mi * 4 + lg, d) = make_float2(A, B);
    }
  }
  __syncthreads();                           // SegT complete

  if (PHASE == 0) {
    if (tid < 256) {
      float PA = 1.f, PB = 0.f;
      #pragma unroll
      for (int s = 0; s < 16; s++) {
        float2 v = *seg_ptr(segt, s, tid);
        PB = v.x * PB + v.y;
        PA *= v.x;
      }
      Ap[(size_t)cb * 256 + tid] = PA;
      Bs[(size_t)cb * 256 + tid] = PB;
    }
    return;
  }

  // ---- PHASE 1: exclusive prefix over 16 segs ----
  if (tid < 256) {
    float PA = 1.f, PB = 0.f;
    #pragma unroll
    for (int s = 0; s < 16; s++) {
      float2* p = seg_ptr(segt, s, tid);
      float2 v = *p;
      *p = make_float2(PA, PB);
      PB = v.x * PB + v.y;
      PA *= v.x;
    }
  }
  __syncthreads();                           // exclusive prefixes ready

  // ---- read own prefixes + carry ----
  float ea[2][4], eb[2][4], h0v[4];
  #pragma unroll
  for (int ni = 0; ni < 4; ni++) {
    const int d = wc * 64 + ni * 16 + l15;
    h0v[ni] = carry[(size_t)cb * 256 + d];
    #pragma unroll
    for (int mi = 0; mi < 2; mi++) {
      float2 e = *seg_ptr(segt, wr * 8 + mi * 4 + lg, d);
      ea[mi][ni] = e.x; eb[mi][ni] = e.y;
    }
  }
  __syncthreads();                           // SegT reads done; As writable

  // ---- rebuild h1 tile into As (bf16 swizzled) ----
  #pragma unroll
  for (int ni = 0; ni < 4; ni++) {
    const int d = wc * 64 + ni * 16 + l15;
    char* sub = (char*)As + (d >> 6) * 8192;
    const int kl2 = (d & 63) * 2;
    #pragma unroll
    for (int mi = 0; mi < 2; mi++) {
      float h = ea[mi][ni] * h0v[ni] + eb[mi][ni];
      #pragma unroll
      for (int r = 0; r < 4; r++) {
        h = accz[mi][ni][r] * h + acch[mi][ni][r];
        const int t = wr * 32 + mi * 16 + lg * 4 + r;
        *(u16*)(sub + ((t * 128 + kl2) ^ ((t & 7) << 4))) = f2bf(h);
      }
    }
  }

  #pragma unroll
  for (int i = 0; i < 2; i++)
    #pragma unroll
    for (int j = 0; j < 4; j++) {
      f32x4 zz = {0.f, 0.f, 0.f, 0.f};
      accz[i][j] = zz; acch[i][j] = zz;
    }

  __syncthreads();                           // h-tile ready (full drain -> vmcnt 0)
  gemm_pipe3(1, WtSb, As, Pb, w, wr, wc, l15, lg, lane, accz, acch);
  __syncthreads();                           // As free for SegT

  // ---- layer-1 gates -> SegT -> totals -> Ap1/Bs1 ----
  #pragma unroll
  for (int ni = 0; ni < 4; ni++) {
    const int d = wc * 64 + ni * 16 + l15;
    const float bzv = bz1[d];
    const float bhv = bh1[d];
    #pragma unroll
    for (int mi = 0; mi < 2; mi++) {
      float A = 1.f, B = 0.f;
      #pragma unroll
      for (int r = 0; r < 4; r++) {
        float zl = accz[mi][ni][r] + bzv;
        float a = __builtin_amdgcn_rcpf(1.f + __expf(zl));
        float ht = acch[mi][ni][r] + bhv;
        float bb = (1.f - a) * ht;
        B = B * a + bb;
        A *= a;
      }
      *seg_ptr(segt, wr * 8 + mi * 4 + lg, d) = make_float2(A, B);
    }
  }
  __syncthreads();
  if (tid < 256) {
    float PA = 1.f, PB = 0.f;
    #pragma unroll
    for (int s = 0; s < 16; s++) {
      float2 v = *seg_ptr(segt, s, tid);
      PB = v.x * PB + v.y;
      PA *= v.x;
    }
    Ap[(size_t)cb * 256 + tid] = PA;
    Bs[(size_t)cb * 256 + tid] = PB;
  }
}

// ---------- serial cross-chunk compose: carry per chunk ----------
__global__ void scan2_l0(const float* __restrict__ Ap0, const float* __restrict__ Bs0,
                         float* __restrict__ carry) {
  const int g = blockIdx.x * 256 + threadIdx.x;   // 8192 = 32 b * 256 d
  const int b = g >> 8, d = g & 255;
  float h = 0.f;
  for (int c = 0; c < NCH; c++) {
    const size_t idx = (size_t)(b * NCH + c) * 256 + d;
    carry[idx] = h;
    h = Bs0[idx] + Ap0[idx] * h;
  }
}

// ---------- layer-1 final: serial over chunk locals -> hlast ----------
__global__ void scan2_l1(const float* __restrict__ Ap1, const float* __restrict__ Bs1,
                         float* __restrict__ hlast) {
  const int g = blockIdx.x * 256 + threadIdx.x;   // 8192
  const int b = g >> 8, d = g & 255;
  float h = 0.f;
  for (int c = 0; c < NCH; c++) {
    const size_t idx = (size_t)(b * NCH + c) * 256 + d;
    h = Bs1[idx] + Ap1[idx] * h;
  }
  hlast[b * 256 + d] = h;
}

__global__ void cls_kernel(const float* __restrict__ hlast, const float* __restrict__ Wo,
                           const float* __restrict__ bo, float* __restrict__ out) {
  const int t = threadIdx.x;       // 256 = 32 b * 8 classes
  const int b = t >> 3, c = t & 7;
  float acc = bo[c];
  for (int d = 0; d < 256; d++) acc += hlast[b * 256 + d] * Wo[d * 8 + c];
  out[t] = acc;
}

extern "C" void kernel_launch(void* const* d_in, const int* in_sizes, int n_in,
                              void* d_out, int out_size, void* d_ws, size_t ws_size,
                              hipStream_t stream) {
  (void)in_sizes; (void)n_in; (void)out_size; (void)ws_size;
  const int*   x   = (const int*)d_in[0];
  const float* emb = (const float*)d_in[1];
  const float* Wz  = (const float*)d_in[2];
  const float* bz  = (const float*)d_in[3];
  const float* Wh  = (const float*)d_in[4];
  const float* bh  = (const float*)d_in[5];
  const float* Wo  = (const float*)d_in[6];
  const float* bo  = (const float*)d_in[7];
  float* out = (float*)d_out;
  char* ws = (char*)d_ws;

  // workspace (~38.3 MB; ws = 256 MiB)
  u16*   embq  = (u16*)  (ws);                      // 16,384,000 (pad to 16 MiB)
  u16*   WtS   = (u16*)  (ws + 16777216ull);        //    524,288
  float* Ap0   = (float*)(ws + 17301504ull);        //  4,194,304
  float* Bs0   = (float*)(ws + 21495808ull);        //  4,194,304
  float* carry = (float*)(ws + 25690112ull);        //  4,194,304
  float* Ap1   = (float*)(ws + 29884416ull);        //  4,194,304
  float* Bs1   = (float*)(ws + 34078720ull);        //  4,194,304
  float* hlast = (float*)(ws + 38273024ull);        //     32,768

  embq_kernel<<<8000, 256, 0, stream>>>(emb, embq);
  wt_kernel<<<1024, 256, 0, stream>>>(Wz, Wh, WtS);

  gru_kernel<0><<<NBLK, 512, 0, stream>>>(
      x, embq, WtS, bz, bh, bz + 256, bh + 256, nullptr, Ap0, Bs0);
  scan2_l0<<<32, 256, 0, stream>>>(Ap0, Bs0, carry);
  gru_kernel<1><<<NBLK, 512, 0, stream>>>(
      x, embq, WtS, bz, bh, bz + 256, bh + 256, carry, Ap1, Bs1);

  scan2_l1<<<32, 256, 0, stream>>>(Ap1, Bs1, hlast);
  cls_kernel<<<1, 256, 0, stream>>>(hlast, Wo, bo, out);
}

// Round 17
// 291.739 us; speedup vs baseline: 1.9290x; 1.0680x over previous
//
#include <hip/hip_runtime.h>
#include <stdint.h>

#define SEQ 8192
#define CS 64                       // chunk length == block row tile
#define NCH 128                     // chunks per sequence
#define NBLK 4096                   // 32 batches * 128 chunks

typedef float f32x4 __attribute__((ext_vector_type(4)));
typedef short short8 __attribute__((ext_vector_type(8)));
typedef unsigned short u16;
typedef u16 ushort8 __attribute__((ext_vector_type(8)));
typedef u16 ushort4v __attribute__((ext_vector_type(4)));

__device__ __forceinline__ u16 f2bf(float f) {
  uint32_t u = __float_as_uint(f);
  u += 0x7fffu + ((u >> 16) & 1u);   // round-to-nearest-even
  return (u16)(u >> 16);
}

// async 16B global->LDS (lds dest wave-uniform base; HW adds lane*16)
__device__ __forceinline__ void gld16(void* lds, const void* g) {
  __builtin_amdgcn_global_load_lds(
      (const __attribute__((address_space(1))) uint32_t*)g,
      (__attribute__((address_space(3))) uint32_t*)lds, 16, 0, 0);
}

// ---------- emb f32 -> bf16 table (one-time) ----------
__global__ void embq_kernel(const float* __restrict__ emb, u16* __restrict__ embq) {
  int i = (blockIdx.x * 256 + threadIdx.x) * 4;   // 8,192,000 elements exactly
  float4 v = *(const float4*)(emb + i);
  ushort4v p;
  p[0] = f2bf(v.x); p[1] = f2bf(v.y); p[2] = f2bf(v.z); p[3] = f2bf(v.w);
  *(ushort4v*)(embq + i) = p;
}

// ---------- weight preprocess: f32 [l][k][d] -> bf16 swizzled 4KB BK=32 tiles ----------
// WtS: 128 tiles of 4096 BYTES, tile index (mat*4 + dh)*8 + k32, in-tile [64 dloc][32 kl],
// byte = dloc*64 + ((kl*2) ^ (((dloc>>1)&3)<<4)).  mat: 0=Wz l0,1=Wz l1,2=Wh l0,3=Wh l1
__global__ void wt_kernel(const float* __restrict__ Wz, const float* __restrict__ Wh,
                          u16* __restrict__ WtS) {
  int idx = blockIdx.x * 256 + threadIdx.x;   // 4*65536
  int d = idx & 255;
  int k = (idx >> 8) & 255;
  int m = idx >> 16;
  const float* src = (m < 2 ? Wz : Wh) + (size_t)(m & 1) * 65536;
  float v = src[k * 256 + d];
  int dh = d >> 6, dloc = d & 63, k32 = k >> 5, kl = k & 31;
  size_t tile = ((size_t)(m * 4 + dh) * 8 + k32) * 4096;   // BYTES
  size_t byte = (size_t)(dloc * 64 + ((kl * 2) ^ (((dloc >> 1) & 3) << 4)));
  *(u16*)((char*)WtS + tile + byte) = f2bf(v);
}

// ---- stage ONE wave's private 4KB dh-tile (dh = wave id) for (mat, k32): 4 gld16 ----
__device__ __forceinline__ void stage32(char* dst_wave, const char* WtSb, int mat, int k32,
                                        int w, int lane) {
  const char* src = WtSb + ((size_t)((mat * 4 + w) * 8 + k32)) * 4096 + lane * 16;
  #pragma unroll
  for (int i = 0; i < 4; i++)
    gld16(dst_wave + i * 1024, src + i * 1024);
}

// ---- A-fragment load for one k32: 4 m-frags covering all 64 rows ----
__device__ __forceinline__ void load_fa(const u16* As, int k32, int l15, int lg,
                                        short8 (&fa)[4]) {
  const int xm = (l15 & 7) << 4;
  const int kt = k32 >> 1, ks = k32 & 1;
  #pragma unroll
  for (int mi = 0; mi < 4; mi++)
    fa[mi] = *(const short8*)((const char*)As + kt * 8192 +
               (((mi * 16 + l15) * 128 + ks * 64 + lg * 16) ^ xm));
}

// ---- one 32-k MFMA step (16 MFMAs/wave) from the wave's private 4KB B tile ----
__device__ __forceinline__ void mfma_frags(const char* Pw, const short8 (&fa)[4],
    int l15, int lg, f32x4 (&acc)[4][4])
{
  #pragma unroll
  for (int ni = 0; ni < 4; ni++) {
    const int dloc = ni * 16 + l15;
    const int off = dloc * 64 + ((lg * 16) ^ (((dloc >> 1) & 3) << 4));
    short8 fb = *(const short8*)(Pw + off);
    #pragma unroll
    for (int mi = 0; mi < 4; mi++)
      acc[mi][ni] = __builtin_amdgcn_mfma_f32_16x16x32_bf16(fa[mi], fb, acc[mi][ni], 0, 0, 0);
  }
}

// ---- barrier-free tri-buffered counted-vmcnt pipeline ----
// 16 stages j=0..15: mat = z if j even else h; k32 = j>>1; buffer j%3.
// B staging is WAVE-PRIVATE (wave w writes & reads only its 4KB region) -> no s_barrier
// needed in the k-loop; per-wave vmcnt(4) orders gld16 -> ds_read (stage = 4 loads).
// Precondition: vmcnt==0 at entry (guaranteed by the __syncthreads before the call).
__device__ __forceinline__ void gemm_pipe3(int lsel, const char* WtSb, const u16* As,
    char* Pw, int w, int l15, int lg, int lane,
    f32x4 (&accz)[4][4], f32x4 (&acch)[4][4])
{
  stage32(Pw,         WtSb, lsel,     0, w, lane);   // j=0 (z, k32=0) -> buf0
  stage32(Pw + 16384, WtSb, 2 + lsel, 0, w, lane);   // j=1 (h, k32=0) -> buf1
  short8 fa[4];
  #pragma unroll
  for (int i = 0; i < 16; ++i) {
    // outstanding before wait = stages {i, i+1} = 8 loads -> vmcnt(4) proves stage(i) landed;
    // tail i=15: only stage 15 outstanding -> vmcnt(0)
    if (i < 15) asm volatile("s_waitcnt vmcnt(4)" ::: "memory");
    else        asm volatile("s_waitcnt vmcnt(0)" ::: "memory");
    __builtin_amdgcn_sched_barrier(0);               // keep reads below the wait
    if (i + 2 < 16)
      stage32(Pw + ((i + 2) % 3) * 16384, WtSb,
              ((i + 2) & 1) ? (2 + lsel) : lsel, (i + 2) >> 1, w, lane);
    if ((i & 1) == 0) {
      load_fa(As, i >> 1, l15, lg, fa);
      mfma_frags(Pw + (i % 3) * 16384, fa, l15, lg, accz);
    } else {
      mfma_frags(Pw + (i % 3) * 16384, fa, l15, lg, acch);
    }
  }
}

// SegT addressing (overlays As): seg row 2048B, XOR-swizzled by seg to spread banks
__device__ __forceinline__ float2* seg_ptr(char* segt, int s, int d) {
  return (float2*)(segt + s * 2048 + ((d * 8) ^ (s << 4)));
}

// ---------- unified GEMM kernel ----------
// Block: 256 threads (4 waves; wave w owns ALL 64 rows x cols [64w, 64w+64)), K=256.
// PHASE 0: gemm0 -> chunk-local (A,B) totals -> Ap0/Bs0.
// PHASE 1: gemm0 recompute (a,b in regs) + carry -> rebuild h1 in LDS -> gemm1 -> Ap1/Bs1.
template<int PHASE>
__global__ __launch_bounds__(256, 2)
void gru_kernel(const int* __restrict__ x, const u16* __restrict__ embq,
                const u16* __restrict__ WtS,
                const float* __restrict__ bz0, const float* __restrict__ bh0,
                const float* __restrict__ bz1, const float* __restrict__ bh1,
                const float* __restrict__ carry,
                float* __restrict__ Ap, float* __restrict__ Bs)
{
  __shared__ __align__(16) u16 As[16384];    // 32KB: 4 kt-subtiles [64t][64k] swz; SegT overlay
  __shared__ __align__(16) char Pb[49152];   // 48KB: 3 bufs x (4 waves x 4KB private)

  const int tid = threadIdx.x;
  const int lane = tid & 63;
  const int w = tid >> 6;                    // wave = col-group, owns d in [64w, 64w+64)
  const int l15 = lane & 15, lg = lane >> 4;
  const int cb = blockIdx.x;
  const int b = cb >> 7, c = cb & (NCH - 1);
  const char* WtSb = (const char*)WtS;
  char* segt = (char*)As;
  char* Pw = Pb + w * 4096;                  // wave's private region within each 16KB buf

  // ---- A gather: 64 rows x 256 k; thread = (row sm=tid>>2, 64-k quarter kq=tid&3) ----
  {
    const int sm = tid >> 2, kq = tid & 3;
    const int tok = x[b * SEQ + c * CS + sm];
    const u16* src = embq + (size_t)tok * 256 + kq * 64;
    char* sub = (char*)As + kq * 8192;
    const int swz = (sm & 7) << 4;
    #pragma unroll
    for (int j = 0; j < 8; j++) {
      ushort8 p = *(const ushort8*)(src + j * 8);
      *(ushort8*)(sub + ((sm * 128 + j * 16) ^ swz)) = p;
    }
  }

  f32x4 accz[4][4], acch[4][4];
  #pragma unroll
  for (int i = 0; i < 4; i++)
    #pragma unroll
    for (int j = 0; j < 4; j++) {
      f32x4 zz = {0.f, 0.f, 0.f, 0.f};
      accz[i][j] = zz; acch[i][j] = zz;
    }

  __syncthreads();                           // As ready (full drain -> vmcnt 0 at pipe entry)
  gemm_pipe3(0, WtSb, As, Pw, w, l15, lg, lane, accz, acch);
  __syncthreads();                           // all MFMA done; As free for SegT

  // ---- layer-0 gates -> SegT (PHASE1 keeps a,b in regs) ----
  #pragma unroll
  for (int ni = 0; ni < 4; ni++) {
    const int d = w * 64 + ni * 16 + l15;
    const float bzv = bz0[d];
    const float bhv = bh0[d];
    #pragma unroll
    for (int mi = 0; mi < 4; mi++) {
      float A = 1.f, B = 0.f;
      #pragma unroll
      for (int r = 0; r < 4; r++) {
        float zl = accz[mi][ni][r] + bzv;
        float a = __builtin_amdgcn_rcpf(1.f + __expf(zl));   // 1 - sigmoid(zl)
        float ht = acch[mi][ni][r] + bhv;
        float bb = (1.f - a) * ht;
        if (PHASE == 1) { accz[mi][ni][r] = a; acch[mi][ni][r] = bb; }
        B = B * a + bb;
        A *= a;
      }
      *seg_ptr(segt, mi * 4 + lg, d) = make_float2(A, B);    // seg = t/4
    }
  }
  __syncthreads();                           // SegT complete

  if (PHASE == 0) {
    float PA = 1.f, PB = 0.f;                // all 256 threads: d = tid
    #pragma unroll
    for (int s = 0; s < 16; s++) {
      float2 v = *seg_ptr(segt, s, tid);
      PB = v.x * PB + v.y;
      PA *= v.x;
    }
    Ap[(size_t)cb * 256 + tid] = PA;
    Bs[(size_t)cb * 256 + tid] = PB;
    return;
  }

  // ---- PHASE 1: exclusive prefix over 16 segs (thread owns d = tid) ----
  {
    float PA = 1.f, PB = 0.f;
    #pragma unroll
    for (int s = 0; s < 16; s++) {
      float2* p = seg_ptr(segt, s, tid);
      float2 v = *p;
      *p = make_float2(PA, PB);
      PB = v.x * PB + v.y;
      PA *= v.x;
    }
  }
  __syncthreads();                           // exclusive prefixes ready

  // ---- read own prefixes + carry ----
  float ea[4][4], eb[4][4], h0v[4];
  #pragma unroll
  for (int ni = 0; ni < 4; ni++) {
    const int d = w * 64 + ni * 16 + l15;
    h0v[ni] = carry[(size_t)cb * 256 + d];
    #pragma unroll
    for (int mi = 0; mi < 4; mi++) {
      float2 e = *seg_ptr(segt, mi * 4 + lg, d);
      ea[mi][ni] = e.x; eb[mi][ni] = e.y;
    }
  }
  __syncthreads();                           // SegT reads done; As writable

  // ---- rebuild h1 tile into As (bf16 swizzled) ----
  #pragma unroll
  for (int ni = 0; ni < 4; ni++) {
    const int d = w * 64 + ni * 16 + l15;
    char* sub = (char*)As + (d >> 6) * 8192; // == w*8192
    const int kl2 = (d & 63) * 2;
    #pragma unroll
    for (int mi = 0; mi < 4; mi++) {
      float h = ea[mi][ni] * h0v[ni] + eb[mi][ni];
      #pragma unroll
      for (int r = 0; r < 4; r++) {
        h = accz[mi][ni][r] * h + acch[mi][ni][r];
        const int t = mi * 16 + lg * 4 + r;
        *(u16*)(sub + ((t * 128 + kl2) ^ ((t & 7) << 4))) = f2bf(h);
      }
    }
  }

  #pragma unroll
  for (int i = 0; i < 4; i++)
    #pragma unroll
    for (int j = 0; j < 4; j++) {
      f32x4 zz = {0.f, 0.f, 0.f, 0.f};
      accz[i][j] = zz; acch[i][j] = zz;
    }

  __syncthreads();                           // h-tile ready (full drain -> vmcnt 0)
  gemm_pipe3(1, WtSb, As, Pw, w, l15, lg, lane, accz, acch);
  __syncthreads();                           // As free for SegT

  // ---- layer-1 gates -> SegT -> totals -> Ap1/Bs1 ----
  #pragma unroll
  for (int ni = 0; ni < 4; ni++) {
    const int d = w * 64 + ni * 16 + l15;
    const float bzv = bz1[d];
    const float bhv = bh1[d];
    #pragma unroll
    for (int mi = 0; mi < 4; mi++) {
      float A = 1.f, B = 0.f;
      #pragma unroll
      for (int r = 0; r < 4; r++) {
        float zl = accz[mi][ni][r] + bzv;
        float a = __builtin_amdgcn_rcpf(1.f + __expf(zl));
        float ht = acch[mi][ni][r] + bhv;
        float bb = (1.f - a) * ht;
        B = B * a + bb;
        A *= a;
      }
      *seg_ptr(segt, mi * 4 + lg, d) = make_float2(A, B);
    }
  }
  __syncthreads();
  {
    float PA = 1.f, PB = 0.f;
    #pragma unroll
    for (int s = 0; s < 16; s++) {
      float2 v = *seg_ptr(segt, s, tid);
      PB = v.x * PB + v.y;
      PA *= v.x;
    }
    Ap[(size_t)cb * 256 + tid] = PA;
    Bs[(size_t)cb * 256 + tid] = PB;
  }
}

// ---------- serial cross-chunk compose: carry per chunk ----------
__global__ void scan2_l0(const float* __restrict__ Ap0, const float* __restrict__ Bs0,
                         float* __restrict__ carry) {
  const int g = blockIdx.x * 256 + threadIdx.x;   // 8192 = 32 b * 256 d
  const int b = g >> 8, d = g & 255;
  float h = 0.f;
  for (int c = 0; c < NCH; c++) {
    const size_t idx = (size_t)(b * NCH + c) * 256 + d;
    carry[idx] = h;
    h = Bs0[idx] + Ap0[idx] * h;
  }
}

// ---------- layer-1 final: serial over chunk locals -> hlast ----------
__global__ void scan2_l1(const float* __restrict__ Ap1, const float* __restrict__ Bs1,
                         float* __restrict__ hlast) {
  const int g = blockIdx.x * 256 + threadIdx.x;   // 8192
  const int b = g >> 8, d = g & 255;
  float h = 0.f;
  for (int c = 0; c < NCH; c++) {
    const size_t idx = (size_t)(b * NCH + c) * 256 + d;
    h = Bs1[idx] + Ap1[idx] * h;
  }
  hlast[b * 256 + d] = h;
}

__global__ void cls_kernel(const float* __restrict__ hlast, const float* __restrict__ Wo,
                           const float* __restrict__ bo, float* __restrict__ out) {
  const int t = threadIdx.x;       // 256 = 32 b * 8 classes
  const int b = t >> 3, c = t & 7;
  float acc = bo[c];
  for (int d = 0; d < 256; d++) acc += hlast[b * 256 + d] * Wo[d * 8 + c];
  out[t] = acc;
}

extern "C" void kernel_launch(void* const* d_in, const int* in_sizes, int n_in,
                              void* d_out, int out_size, void* d_ws, size_t ws_size,
                              hipStream_t stream) {
  (void)in_sizes; (void)n_in; (void)out_size; (void)ws_size;
  const int*   x   = (const int*)d_in[0];
  const float* emb = (const float*)d_in[1];
  const float* Wz  = (const float*)d_in[2];
  const float* bz  = (const float*)d_in[3];
  const float* Wh  = (const float*)d_in[4];
  const float* bh  = (const float*)d_in[5];
  const float* Wo  = (const float*)d_in[6];
  const float* bo  = (const float*)d_in[7];
  float* out = (float*)d_out;
  char* ws = (char*)d_ws;

  // workspace (~38.3 MB; ws = 256 MiB)
  u16*   embq  = (u16*)  (ws);                      // 16,384,000 (pad to 16 MiB)
  u16*   WtS   = (u16*)  (ws + 16777216ull);        //    524,288
  float* Ap0   = (float*)(ws + 17301504ull);        //  4,194,304
  float* Bs0   = (float*)(ws + 21495808ull);        //  4,194,304
  float* carry = (float*)(ws + 25690112ull);        //  4,194,304
  float* Ap1   = (float*)(ws + 29884416ull);        //  4,194,304
  float* Bs1   = (float*)(ws + 34078720ull);        //  4,194,304
  float* hlast = (float*)(ws + 38273024ull);        //     32,768

  embq_kernel<<<8000, 256, 0, stream>>>(emb, embq);
  wt_kernel<<<1024, 256, 0, stream>>>(Wz, Wh, WtS);

  gru_kernel<0><<<NBLK, 256, 0, stream>>>(
      x, embq, WtS, bz, bh, bz + 256, bh + 256, nullptr, Ap0, Bs0);
  scan2_l0<<<32, 256, 0, stream>>>(Ap0, Bs0, carry);
  gru_kernel<1><<<NBLK, 256, 0, stream>>>(
      x, embq, WtS, bz, bh, bz + 256, bh + 256, carry, Ap1, Bs1);

  scan2_l1<<<32, 256, 0, stream>>>(Ap1, Bs1, hlast);
  cls_kernel<<<1, 256, 0, stream>>>(hlast, Wo, bo, out);
}